// Round 7
// baseline (170.551 us; speedup 1.0000x reference)
//
#include <hip/hip_runtime.h>
#include <cstdint>
#include <cstddef>

#define AUDIO_DIM 512
#define TEXT_DIM  768
#define HIDDEN    512
#define BATCH     8
#define ALEN      2048
#define TLEN      512

typedef _Float16 half8 __attribute__((ext_vector_type(8)));
typedef _Float16 half4_t __attribute__((ext_vector_type(4)));
typedef float floatx4 __attribute__((ext_vector_type(4)));

#define AS1 __attribute__((address_space(1)))
#define AS3 __attribute__((address_space(3)))

// Async global->LDS, 16B per lane. LDS dest = wave-uniform base + lane*16.
__device__ __forceinline__ void gload_lds16(const void* g, void* l) {
    __builtin_amdgcn_global_load_lds((const AS1 void*)g, (AS3 void*)l, 16, 0, 0);
}

// XOR swizzle: 16B chunk c of row r lives at slot c ^ swz(r).
__device__ __forceinline__ int swz(int r) { return (r >> 1) & 3; }

// Counted vmcnt waits (T4, m135-verified semantics).
#define VMCNT(N) asm volatile("s_waitcnt vmcnt(" #N ")" ::: "memory")

// ---------------------------------------------------------------------------
// prep: text fp32->f16 + weight transposes ONLY (audio cvt fused into the
// Q-GEMM's A-staging — saves the 50 MB audio round-trip; R6-measured −21 µs
// on the non-attn portion).
//   blocks [0,3072)     : text  fp32 -> f16
//   blocks [3072,3328)  : Wq transpose -> Wq_t
//   blocks [3328,3712)  : Wk transpose -> Wk_t
//   blocks [3712,4096)  : Wv transpose -> Wv_t
// ---------------------------------------------------------------------------
__global__ __launch_bounds__(256) void prep(
    const float* __restrict__ text,
    const float* __restrict__ Wq, const float* __restrict__ Wk,
    const float* __restrict__ Wv,
    _Float16* __restrict__ text_h,
    _Float16* __restrict__ Wq_t, _Float16* __restrict__ Wk_t,
    _Float16* __restrict__ Wv_t)
{
    __shared__ _Float16 tt[32 * 33];
    const int bid = blockIdx.x, tid = threadIdx.x;
    if (bid < 3072) {
        int i = bid * 256 + tid;
        float4 v = ((const float4*)text)[i];
        half4_t h;
        h.x = (_Float16)v.x; h.y = (_Float16)v.y; h.z = (_Float16)v.z; h.w = (_Float16)v.w;
        ((half4_t*)text_h)[i] = h;
    } else {
        const float* src; _Float16* dst; int R, lb;
        if (bid < 3328)      { lb = bid - 3072; src = Wq; dst = Wq_t; R = 512; }
        else if (bid < 3712) { lb = bid - 3328; src = Wk; dst = Wk_t; R = 768; }
        else                 { lb = bid - 3712; src = Wv; dst = Wv_t; R = 768; }
        const int C = 512;
        const int c0 = (lb & 15) * 32, r0 = (lb >> 4) * 32;
        const int tx = tid & 31, ty = tid >> 5;   // 32 x 8
#pragma unroll
        for (int i = 0; i < 4; i++) {
            int r = ty + i * 8;
            tt[r * 33 + tx] = (_Float16)src[(size_t)(r0 + r) * C + c0 + tx];
        }
        __syncthreads();
#pragma unroll
        for (int i = 0; i < 4; i++) {
            int r = ty + i * 8;
            dst[(size_t)(c0 + r) * R + r0 + tx] = tt[tx * 33 + r];
        }
    }
}

// ---------------------------------------------------------------------------
// Shared f16 MFMA GEMM body: 128x128 tile, BK=32, 4 waves.
// CVT_A: A is fp32; staged via reg-load + cvt + ds_write (same XOR layout).
// ---------------------------------------------------------------------------
template <bool OUT16, bool ROWBIAS, bool CVT_A>
__device__ __forceinline__ void gemm_body(
    const void* __restrict__ Avp, const _Float16* __restrict__ Bt,
    const float* __restrict__ bias, void* __restrict__ Cp,
    int N, int K, int m0, int n0, _Float16* Asm, _Float16* Bsm)
{
    const int tid = threadIdx.x;
    const int l = tid & 63, w = tid >> 6;
    const int wm = w >> 1, wn = w & 1;
    const int srow = l >> 2, sj = l & 3;
    const int q = l >> 4, c16 = l & 15;

    floatx4 acc[4][4] = {};

    for (int k0 = 0; k0 < K; k0 += 32) {
        if (k0) __syncthreads();
#pragma unroll
        for (int i = 0; i < 2; i++) {
            int rb = (w * 2 + i) * 16;
            int r = rb + srow;
            int cc = sj ^ swz(r);
            if constexpr (CVT_A) {
                const float* Af = (const float*)Avp;
                const float* s = &Af[(size_t)(m0 + r) * K + k0 + cc * 8];
                float4 v0 = *(const float4*)s;
                float4 v1 = *(const float4*)(s + 4);
                half8 h;
                h[0] = (_Float16)v0.x; h[1] = (_Float16)v0.y;
                h[2] = (_Float16)v0.z; h[3] = (_Float16)v0.w;
                h[4] = (_Float16)v1.x; h[5] = (_Float16)v1.y;
                h[6] = (_Float16)v1.z; h[7] = (_Float16)v1.w;
                *(half8*)&Asm[r * 32 + sj * 8] = h;
            } else {
                const _Float16* Ah = (const _Float16*)Avp;
                gload_lds16(Ah + (size_t)(m0 + r) * K + k0 + cc * 8, Asm + rb * 32);
            }
            gload_lds16(Bt + (size_t)(n0 + r) * K + k0 + cc * 8, Bsm + rb * 32);
        }
        __syncthreads();

        half8 af[4], bf[4];
#pragma unroll
        for (int t = 0; t < 4; t++) {
            int rA = wm * 64 + t * 16 + c16;
            af[t] = *(const half8*)&Asm[rA * 32 + ((q ^ swz(rA)) << 3)];
            int rB = wn * 64 + t * 16 + c16;
            bf[t] = *(const half8*)&Bsm[rB * 32 + ((q ^ swz(rB)) << 3)];
        }
#pragma unroll
        for (int mi = 0; mi < 4; mi++)
#pragma unroll
            for (int ni = 0; ni < 4; ni++)
                acc[mi][ni] = __builtin_amdgcn_mfma_f32_16x16x32_f16(
                    af[mi], bf[ni], acc[mi][ni], 0, 0, 0);
    }

    if (OUT16) {
        float bcol[4];
        float brow[4][4];
        if (!ROWBIAS) {
#pragma unroll
            for (int ni = 0; ni < 4; ni++)
                bcol[ni] = bias[n0 + wn * 64 + ni * 16 + c16];
        } else {
#pragma unroll
            for (int mi = 0; mi < 4; mi++) {
                float4 b4 = *(const float4*)&bias[m0 + wm * 64 + mi * 16 + q * 4];
                brow[mi][0] = b4.x; brow[mi][1] = b4.y;
                brow[mi][2] = b4.z; brow[mi][3] = b4.w;
            }
        }
        _Float16* C = (_Float16*)Cp;
#pragma unroll
        for (int ni = 0; ni < 4; ni++) {
            int col = n0 + wn * 64 + ni * 16 + c16;
#pragma unroll
            for (int mi = 0; mi < 4; mi++) {
                int row = m0 + wm * 64 + mi * 16 + q * 4;
#pragma unroll
                for (int r = 0; r < 4; r++) {
                    float b = ROWBIAS ? brow[mi][r] : bcol[ni];
                    C[(size_t)(row + r) * N + col] = (_Float16)(acc[mi][ni][r] + b);
                }
            }
        }
    } else {
        float* C = (float*)Cp;
#pragma unroll
        for (int ni = 0; ni < 4; ni++) {
            int col = n0 + wn * 64 + ni * 16 + c16;
#pragma unroll
            for (int mi = 0; mi < 4; mi++) {
                int row = m0 + wm * 64 + mi * 16 + q * 4;
#pragma unroll
                for (int r = 0; r < 4; r++)
                    C[(size_t)(row + r) * N + col] = acc[mi][ni][r];
            }
        }
    }
}

// ---------------------------------------------------------------------------
// qkv_gemm: 768 blocks, XCD-swizzled tile coords per segment.
// Q-GEMM reads audio fp32 directly (CVT_A staging).
// ---------------------------------------------------------------------------
__global__ __launch_bounds__(256, 3) void qkv_gemm(
    const float* __restrict__ audio, const _Float16* __restrict__ text_h,
    const _Float16* __restrict__ Wq_t, const _Float16* __restrict__ Wk_t,
    const _Float16* __restrict__ Wv_t,
    const float* __restrict__ bq, const float* __restrict__ bk,
    const float* __restrict__ bv,
    _Float16* __restrict__ Qh, _Float16* __restrict__ Kh,
    _Float16* __restrict__ Vt)
{
    __shared__ __align__(16) _Float16 Asm[128 * 32];
    __shared__ __align__(16) _Float16 Bsm[128 * 32];
    const int bid = blockIdx.x;
    if (bid < 512) {
        int t = (bid & 7) * 64 + (bid >> 3);
        gemm_body<true, false, true>(audio, Wq_t, bq, Qh, 512, 512,
                                     (t >> 2) * 128, (t & 3) * 128, Asm, Bsm);
    } else if (bid < 640) {
        int s = bid - 512;
        int t = (s & 7) * 16 + (s >> 3);
        gemm_body<true, false, false>(text_h, Wk_t, bk, Kh, 512, 768,
                                      (t >> 2) * 128, (t & 3) * 128, Asm, Bsm);
    } else {
        int s = bid - 640;
        int t = (s & 7) * 16 + (s >> 3);   // XCD c -> batch z == c
        int z = t >> 4, by = (t >> 2) & 3, bx = t & 3;
        gemm_body<true, true, false>(Wv_t, text_h + (size_t)z * 393216, bv,
                                     Vt + (size_t)z * 262144, 512, 768,
                                     by * 128, bx * 128, Asm, Bsm);
    }
}

// ---------------------------------------------------------------------------
// attn: EXACT R5 schedule (measured 42.6 µs) — R6's lgkm-fence +
// sched_barrier + setprio micro-schedule regressed it to 69 µs (serialized
// the wave, defeated compiler pipelining; m141 failure mode) and is
// reverted. 64 Q-rows/block, 8 waves, 256 blocks = 1 block/CU, per-wave
// private K/V band double-buffered, counted vmcnt(4), 4 barriers total.
// ---------------------------------------------------------------------------
#define STAGE64(SRC, K0, BUF)                                               \
    do {                                                                    \
        _Pragma("unroll")                                                   \
        for (int i_ = 0; i_ < 4; i_++) {                                    \
            int lr_ = i_ * 16 + srow;                                       \
            int cc_ = sj ^ swz(lr_);                                        \
            gload_lds16((SRC) + (size_t)(w * 64 + lr_) * HIDDEN + (K0) + cc_ * 8, \
                        &(BUF)[i_ * 512]);                                  \
        }                                                                   \
    } while (0)

__global__ __launch_bounds__(512, 2) void attn(
    const _Float16* __restrict__ Qh, const _Float16* __restrict__ Kh,
    const _Float16* __restrict__ Vt, const int* __restrict__ mask,
    float* __restrict__ out)
{
    __shared__ __align__(16) _Float16 QPs[64 * 512];      // 64 KB: Q, then P
    __shared__ __align__(16) _Float16 Ks[8][2][64 * 32];  // 64 KB: K, then V
    __shared__ float red[8][64];
    __shared__ float red2[8][64];
    const int tid = threadIdx.x, l = tid & 63, w = tid >> 6;   // w in 0..7
    const int lin = blockIdx.x;
    const int tb = (lin & 7) * 32 + (lin >> 3);   // XCD c -> batch b == c
    const int b = tb >> 5, a0 = (tb & 31) * 64;
    const _Float16* Qb = Qh + (size_t)(b * ALEN + a0) * HIDDEN;
    const _Float16* Kb = Kh + (size_t)b * TLEN * HIDDEN;
    const _Float16* Vb = Vt + (size_t)b * TLEN * HIDDEN;  // [h][t]
    const int srow = l >> 2, sj = l & 3;
    const int q = l >> 4, c16 = l & 15;

    // mask to regs up front (keeps loop vmcnt counts deterministic)
    int mv[4];
#pragma unroll
    for (int ni = 0; ni < 4; ni++)
        mv[ni] = mask[b * TLEN + w * 64 + ni * 16 + c16];

    // ---- stage Q (shared, once): wave w stages rows [w*8, w*8+8).
    // LDS chunk slot s of row r holds global chunk s ^ (r&7)  (chunk=16B).
#pragma unroll
    for (int i = 0; i < 8; i++) {
        int r = w * 8 + i;
        gload_lds16(Qb + (size_t)r * 512 + ((l ^ (r & 7)) << 3), &QPs[r * 512]);
    }
    // K prologue into private double buffer (drained by the barrier too)
    STAGE64(Kb, 0, Ks[w][0]);
    STAGE64(Kb, 32, Ks[w][1]);
    __syncthreads();   // publish Q; vmcnt drains to 0 here

    // ---------------- QK^T: barrier-free, double-buffered ----------------
    floatx4 acc[4][4] = {};
#pragma unroll
    for (int ks = 0; ks < 16; ks++) {
        const int k0 = ks * 32;
        if (ks == 15) { VMCNT(0); } else { VMCNT(4); }
        half8 af[4], bf[4];
        const _Float16* kb = &Ks[w][ks & 1][0];
#pragma unroll
        for (int t = 0; t < 4; t++) {
            int rA = t * 16 + c16;
            af[t] = *(const half8*)&QPs[rA * 512 + ((((k0 >> 3) + q) ^ (rA & 7)) << 3)];
            bf[t] = *(const half8*)&kb[rA * 32 + ((q ^ swz(rA)) << 3)];
        }
#pragma unroll
        for (int mi = 0; mi < 4; mi++)
#pragma unroll
            for (int ni = 0; ni < 4; ni++)
                acc[mi][ni] = __builtin_amdgcn_mfma_f32_16x16x32_f16(
                    af[mi], bf[ni], acc[mi][ni], 0, 0, 0);
        if (ks < 14) STAGE64(Kb, k0 + 64, Ks[w][ks & 1]);   // stage step ks+2
    }

    // V prologue NOW: latency hides under softmax (barrier drains it there)
    STAGE64(Vb, 0, Ks[w][0]);
    STAGE64(Vb, 32, Ks[w][1]);

    // ---------------- mask + softmax ----------------
    const float scale = 0.044194173824159216f;   // 512^-0.5
#pragma unroll
    for (int mi = 0; mi < 4; mi++)
#pragma unroll
        for (int ni = 0; ni < 4; ni++)
#pragma unroll
            for (int r = 0; r < 4; r++)
                acc[mi][ni][r] = mv[ni] ? acc[mi][ni][r] * scale : -1e30f;

    float mx[4][4];
#pragma unroll
    for (int mi = 0; mi < 4; mi++)
#pragma unroll
        for (int r = 0; r < 4; r++) {
            float m = -1e30f;
#pragma unroll
            for (int ni = 0; ni < 4; ni++) m = fmaxf(m, acc[mi][ni][r]);
#pragma unroll
            for (int off = 1; off <= 8; off <<= 1) m = fmaxf(m, __shfl_xor(m, off));
            mx[mi][r] = m;
        }
    if (c16 == 0)
#pragma unroll
        for (int mi = 0; mi < 4; mi++)
#pragma unroll
            for (int r = 0; r < 4; r++) red[w][mi * 16 + q * 4 + r] = mx[mi][r];
    __syncthreads();
#pragma unroll
    for (int mi = 0; mi < 4; mi++)
#pragma unroll
        for (int r = 0; r < 4; r++) {
            int row = mi * 16 + q * 4 + r;
            float m = red[0][row];
#pragma unroll
            for (int ww = 1; ww < 8; ww++) m = fmaxf(m, red[ww][row]);
            mx[mi][r] = m;
        }

    float sm[4][4];
#pragma unroll
    for (int mi = 0; mi < 4; mi++)
#pragma unroll
        for (int r = 0; r < 4; r++) {
            float s = 0.f;
#pragma unroll
            for (int ni = 0; ni < 4; ni++) {
                float e = __expf(acc[mi][ni][r] - mx[mi][r]);
                acc[mi][ni][r] = e;
                s += e;
            }
#pragma unroll
            for (int off = 1; off <= 8; off <<= 1) s += __shfl_xor(s, off);
            sm[mi][r] = s;
        }
    if (c16 == 0)
#pragma unroll
        for (int mi = 0; mi < 4; mi++)
#pragma unroll
            for (int r = 0; r < 4; r++) red2[w][mi * 16 + q * 4 + r] = sm[mi][r];
    __syncthreads();

    // ---------------- P -> LDS (overwrites Q; all Q reads done) ----------
    // Element (row,col) at chunk slot (col>>3) ^ (row&7), offset col&7.
    _Float16* Ps = QPs;
#pragma unroll
    for (int mi = 0; mi < 4; mi++)
#pragma unroll
        for (int r = 0; r < 4; r++) {
            int row = mi * 16 + q * 4 + r;
            float s = red2[0][row];
#pragma unroll
            for (int ww = 1; ww < 8; ww++) s += red2[ww][row];
            float inv = 1.f / s;
#pragma unroll
            for (int ni = 0; ni < 4; ni++) {
                int col = w * 64 + ni * 16 + c16;
                Ps[row * 512 + ((((col >> 3) ^ (row & 7)) << 3) + (col & 7))] =
                    (_Float16)(acc[mi][ni][r] * inv);
            }
        }
    __syncthreads();   // publish P (cross-wave read in PV)

    // ---------------- PV: barrier-free, double-buffered ----------------
    // out[a][h] = sum_t P[a][t] * Vt[h][t]; V in own Ks half-buffers.
    floatx4 oacc[4][4] = {};
#pragma unroll
    for (int ts = 0; ts < 16; ts++) {
        const int t0 = ts * 32;
        if (ts == 15) { VMCNT(0); } else { VMCNT(4); }
        half8 af[4], bf[4];
        const _Float16* vb = &Ks[w][ts & 1][0];
#pragma unroll
        for (int t = 0; t < 4; t++) {
            int rA = t * 16 + c16;
            af[t] = *(const half8*)&Ps[rA * 512 + ((((t0 >> 3) + q) ^ (rA & 7)) << 3)];
            bf[t] = *(const half8*)&vb[rA * 32 + ((q ^ swz(rA)) << 3)];
        }
#pragma unroll
        for (int mi = 0; mi < 4; mi++)
#pragma unroll
            for (int ni = 0; ni < 4; ni++)
                oacc[mi][ni] = __builtin_amdgcn_mfma_f32_16x16x32_f16(
                    af[mi], bf[ni], oacc[mi][ni], 0, 0, 0);
        if (ts < 14) STAGE64(Vb, t0 + 64, Ks[w][ts & 1]);   // stage step ts+2
    }

    // ---------------- epilogue: fp32 out ----------------
    float* Ob = out + (size_t)(b * ALEN + a0) * HIDDEN;
#pragma unroll
    for (int ni = 0; ni < 4; ni++) {
        int col = w * 64 + ni * 16 + c16;
#pragma unroll
        for (int mi = 0; mi < 4; mi++) {
            int row = mi * 16 + q * 4;
#pragma unroll
            for (int r = 0; r < 4; r++)
                Ob[(size_t)(row + r) * HIDDEN + col] = oacc[mi][ni][r];
        }
    }
}

// ---------------------------------------------------------------------------
extern "C" void kernel_launch(void* const* d_in, const int* in_sizes, int n_in,
                              void* d_out, int out_size, void* d_ws, size_t ws_size,
                              hipStream_t stream)
{
    const float* audio = (const float*)d_in[0];   // [8,2048,512]
    const float* text  = (const float*)d_in[1];   // [8,512,768]
    const float* Wq    = (const float*)d_in[2];   // [512,512]
    const float* bq    = (const float*)d_in[3];
    const float* Wk    = (const float*)d_in[4];   // [768,512]
    const float* bk    = (const float*)d_in[5];
    const float* Wv    = (const float*)d_in[6];   // [768,512]
    const float* bv    = (const float*)d_in[7];
    const int*   maskp = (const int*)d_in[8];     // [8,512]
    float* out = (float*)d_out;

    // d_out doubles as f16 scratch until attn overwrites it:
    //   [8.39M .. 16.78M) halfs: Qh
    _Float16* Qh = (_Float16*)d_out + (size_t)8388608;

    // ws layout (halfs)
    _Float16* ws16   = (_Float16*)d_ws;
    _Float16* text_h = ws16;                        // 3,145,728  [B*512][768]
    _Float16* Wq_t   = text_h + 3145728;            //   262,144  [512][512]
    _Float16* Wk_t   = Wq_t + 262144;               //   393,216  [512][768]
    _Float16* Wv_t   = Wk_t + 393216;               //   393,216  [512][768]
    _Float16* Kh     = Wv_t + 393216;               // 2,097,152  [B,512,512]
    _Float16* Vt     = Kh + 2097152;                // 2,097,152  [B,512(h),512(t)]

    // 1) text cvt + weight transposes (audio cvt fused into qkv)
    prep<<<4096, 256, 0, stream>>>(text, Wq, Wk, Wv,
                                   text_h, Wq_t, Wk_t, Wv_t);
    // 2) Q + K + V^T GEMMs in one dispatch (Q reads audio fp32 directly)
    qkv_gemm<<<768, 256, 0, stream>>>(audio, text_h, Wq_t, Wk_t, Wv_t,
                                      bq, bk, bv, Qh, Kh, Vt);
    // 3) fused scores+softmax+PV: 256 blocks x 512 thr, batch-per-XCD
    attn<<<256, 512, 0, stream>>>(Qh, Kh, Vt, maskp, out);
}

// Round 9
// 167.539 us; speedup vs baseline: 1.0180x; 1.0180x over previous
//
#include <hip/hip_runtime.h>
#include <cstdint>
#include <cstddef>

#define AUDIO_DIM 512
#define TEXT_DIM  768
#define HIDDEN    512
#define BATCH     8
#define ALEN      2048
#define TLEN      512

typedef _Float16 half8 __attribute__((ext_vector_type(8)));
typedef _Float16 half4_t __attribute__((ext_vector_type(4)));
typedef float floatx4 __attribute__((ext_vector_type(4)));

#define AS1 __attribute__((address_space(1)))
#define AS3 __attribute__((address_space(3)))

// Async global->LDS, 16B per lane. LDS dest = wave-uniform base + lane*16.
__device__ __forceinline__ void gload_lds16(const void* g, void* l) {
    __builtin_amdgcn_global_load_lds((const AS1 void*)g, (AS3 void*)l, 16, 0, 0);
}

// XOR swizzle: 16B chunk c of row r lives at slot c ^ swz(r).
__device__ __forceinline__ int swz(int r) { return (r >> 1) & 3; }

// Counted vmcnt waits (T4, m135-verified semantics).
#define VMCNT(N) asm volatile("s_waitcnt vmcnt(" #N ")" ::: "memory")

// ---------------------------------------------------------------------------
// prep: text fp32->f16 + weight transposes. All fp32 source reads are
// NON-TEMPORAL (single-use streams; keep them out of L2 so the working
// tensors qkv/attn rely on stay resident). NOTE: the builtin requires a
// native ext_vector type (floatx4), not HIP_vector_type (float4).
//   blocks [0,3072)     : text  fp32 -> f16
//   blocks [3072,3328)  : Wq transpose -> Wq_t
//   blocks [3328,3712)  : Wk transpose -> Wk_t
//   blocks [3712,4096)  : Wv transpose -> Wv_t
// ---------------------------------------------------------------------------
__global__ __launch_bounds__(256) void prep(
    const float* __restrict__ text,
    const float* __restrict__ Wq, const float* __restrict__ Wk,
    const float* __restrict__ Wv,
    _Float16* __restrict__ text_h,
    _Float16* __restrict__ Wq_t, _Float16* __restrict__ Wk_t,
    _Float16* __restrict__ Wv_t)
{
    __shared__ _Float16 tt[32 * 33];
    const int bid = blockIdx.x, tid = threadIdx.x;
    if (bid < 3072) {
        int i = bid * 256 + tid;
        floatx4 v = __builtin_nontemporal_load(&((const floatx4*)text)[i]);
        half4_t h;
        h.x = (_Float16)v.x; h.y = (_Float16)v.y; h.z = (_Float16)v.z; h.w = (_Float16)v.w;
        ((half4_t*)text_h)[i] = h;
    } else {
        const float* src; _Float16* dst; int R, lb;
        if (bid < 3328)      { lb = bid - 3072; src = Wq; dst = Wq_t; R = 512; }
        else if (bid < 3712) { lb = bid - 3328; src = Wk; dst = Wk_t; R = 768; }
        else                 { lb = bid - 3712; src = Wv; dst = Wv_t; R = 768; }
        const int C = 512;
        const int c0 = (lb & 15) * 32, r0 = (lb >> 4) * 32;
        const int tx = tid & 31, ty = tid >> 5;   // 32 x 8
#pragma unroll
        for (int i = 0; i < 4; i++) {
            int r = ty + i * 8;
            tt[r * 33 + tx] =
                (_Float16)__builtin_nontemporal_load(&src[(size_t)(r0 + r) * C + c0 + tx]);
        }
        __syncthreads();
#pragma unroll
        for (int i = 0; i < 4; i++) {
            int r = ty + i * 8;
            dst[(size_t)(c0 + r) * R + r0 + tx] = tt[tx * 33 + r];
        }
    }
}

// ---------------------------------------------------------------------------
// Shared f16 MFMA GEMM body: 128x128 tile, BK=32, 4 waves.
// CVT_A: A is fp32; staged via NON-TEMPORAL reg-load + cvt + ds_write.
// (R7 lesson: the fp32 audio stream is 4.2 MB/XCD — plain loads evict the
// K/V/Qh working set and attn degrades 42.6->68.5 µs. nt keeps L2 clean.)
// ---------------------------------------------------------------------------
template <bool OUT16, bool ROWBIAS, bool CVT_A>
__device__ __forceinline__ void gemm_body(
    const void* __restrict__ Avp, const _Float16* __restrict__ Bt,
    const float* __restrict__ bias, void* __restrict__ Cp,
    int N, int K, int m0, int n0, _Float16* Asm, _Float16* Bsm)
{
    const int tid = threadIdx.x;
    const int l = tid & 63, w = tid >> 6;
    const int wm = w >> 1, wn = w & 1;
    const int srow = l >> 2, sj = l & 3;
    const int q = l >> 4, c16 = l & 15;

    floatx4 acc[4][4] = {};

    for (int k0 = 0; k0 < K; k0 += 32) {
        if (k0) __syncthreads();
#pragma unroll
        for (int i = 0; i < 2; i++) {
            int rb = (w * 2 + i) * 16;
            int r = rb + srow;
            int cc = sj ^ swz(r);
            if constexpr (CVT_A) {
                const float* Af = (const float*)Avp;
                const float* s = &Af[(size_t)(m0 + r) * K + k0 + cc * 8];
                floatx4 v0 = __builtin_nontemporal_load((const floatx4*)s);
                floatx4 v1 = __builtin_nontemporal_load((const floatx4*)(s + 4));
                half8 h;
                h[0] = (_Float16)v0.x; h[1] = (_Float16)v0.y;
                h[2] = (_Float16)v0.z; h[3] = (_Float16)v0.w;
                h[4] = (_Float16)v1.x; h[5] = (_Float16)v1.y;
                h[6] = (_Float16)v1.z; h[7] = (_Float16)v1.w;
                *(half8*)&Asm[r * 32 + sj * 8] = h;
            } else {
                const _Float16* Ah = (const _Float16*)Avp;
                gload_lds16(Ah + (size_t)(m0 + r) * K + k0 + cc * 8, Asm + rb * 32);
            }
            gload_lds16(Bt + (size_t)(n0 + r) * K + k0 + cc * 8, Bsm + rb * 32);
        }
        __syncthreads();

        half8 af[4], bf[4];
#pragma unroll
        for (int t = 0; t < 4; t++) {
            int rA = wm * 64 + t * 16 + c16;
            af[t] = *(const half8*)&Asm[rA * 32 + ((q ^ swz(rA)) << 3)];
            int rB = wn * 64 + t * 16 + c16;
            bf[t] = *(const half8*)&Bsm[rB * 32 + ((q ^ swz(rB)) << 3)];
        }
#pragma unroll
        for (int mi = 0; mi < 4; mi++)
#pragma unroll
            for (int ni = 0; ni < 4; ni++)
                acc[mi][ni] = __builtin_amdgcn_mfma_f32_16x16x32_f16(
                    af[mi], bf[ni], acc[mi][ni], 0, 0, 0);
    }

    if (OUT16) {
        float bcol[4];
        float brow[4][4];
        if (!ROWBIAS) {
#pragma unroll
            for (int ni = 0; ni < 4; ni++)
                bcol[ni] = bias[n0 + wn * 64 + ni * 16 + c16];
        } else {
#pragma unroll
            for (int mi = 0; mi < 4; mi++) {
                float4 b4 = *(const float4*)&bias[m0 + wm * 64 + mi * 16 + q * 4];
                brow[mi][0] = b4.x; brow[mi][1] = b4.y;
                brow[mi][2] = b4.z; brow[mi][3] = b4.w;
            }
        }
        _Float16* C = (_Float16*)Cp;
#pragma unroll
        for (int ni = 0; ni < 4; ni++) {
            int col = n0 + wn * 64 + ni * 16 + c16;
#pragma unroll
            for (int mi = 0; mi < 4; mi++) {
                int row = m0 + wm * 64 + mi * 16 + q * 4;
#pragma unroll
                for (int r = 0; r < 4; r++) {
                    float b = ROWBIAS ? brow[mi][r] : bcol[ni];
                    C[(size_t)(row + r) * N + col] = (_Float16)(acc[mi][ni][r] + b);
                }
            }
        }
    } else {
        float* C = (float*)Cp;
#pragma unroll
        for (int ni = 0; ni < 4; ni++) {
            int col = n0 + wn * 64 + ni * 16 + c16;
#pragma unroll
            for (int mi = 0; mi < 4; mi++) {
                int row = m0 + wm * 64 + mi * 16 + q * 4;
#pragma unroll
                for (int r = 0; r < 4; r++)
                    C[(size_t)(row + r) * N + col] = acc[mi][ni][r];
            }
        }
    }
}

// ---------------------------------------------------------------------------
// qkv_gemm: 768 blocks, XCD-swizzled tile coords per segment.
// Q-GEMM reads audio fp32 directly (CVT_A staging, now nt).
// ---------------------------------------------------------------------------
__global__ __launch_bounds__(256, 3) void qkv_gemm(
    const float* __restrict__ audio, const _Float16* __restrict__ text_h,
    const _Float16* __restrict__ Wq_t, const _Float16* __restrict__ Wk_t,
    const _Float16* __restrict__ Wv_t,
    const float* __restrict__ bq, const float* __restrict__ bk,
    const float* __restrict__ bv,
    _Float16* __restrict__ Qh, _Float16* __restrict__ Kh,
    _Float16* __restrict__ Vt)
{
    __shared__ __align__(16) _Float16 Asm[128 * 32];
    __shared__ __align__(16) _Float16 Bsm[128 * 32];
    const int bid = blockIdx.x;
    if (bid < 512) {
        int t = (bid & 7) * 64 + (bid >> 3);
        gemm_body<true, false, true>(audio, Wq_t, bq, Qh, 512, 512,
                                     (t >> 2) * 128, (t & 3) * 128, Asm, Bsm);
    } else if (bid < 640) {
        int s = bid - 512;
        int t = (s & 7) * 16 + (s >> 3);
        gemm_body<true, false, false>(text_h, Wk_t, bk, Kh, 512, 768,
                                      (t >> 2) * 128, (t & 3) * 128, Asm, Bsm);
    } else {
        int s = bid - 640;
        int t = (s & 7) * 16 + (s >> 3);   // XCD c -> batch z == c
        int z = t >> 4, by = (t >> 2) & 3, bx = t & 3;
        gemm_body<true, true, false>(Wv_t, text_h + (size_t)z * 393216, bv,
                                     Vt + (size_t)z * 262144, 512, 768,
                                     by * 128, bx * 128, Asm, Bsm);
    }
}

// ---------------------------------------------------------------------------
// attn: EXACT R5 schedule (64 Q-rows/block, 8 waves, 256 blocks = 1/CU,
// per-wave private K/V band double-buffered, counted vmcnt(4), 4 barriers).
// Only change vs R5/R7: fp32 out stores are NON-TEMPORAL (33.5 MB, never
// re-read; stop them evicting the K/V/P working set mid-kernel).
// ---------------------------------------------------------------------------
#define STAGE64(SRC, K0, BUF)                                               \
    do {                                                                    \
        _Pragma("unroll")                                                   \
        for (int i_ = 0; i_ < 4; i_++) {                                    \
            int lr_ = i_ * 16 + srow;                                       \
            int cc_ = sj ^ swz(lr_);                                        \
            gload_lds16((SRC) + (size_t)(w * 64 + lr_) * HIDDEN + (K0) + cc_ * 8, \
                        &(BUF)[i_ * 512]);                                  \
        }                                                                   \
    } while (0)

__global__ __launch_bounds__(512, 2) void attn(
    const _Float16* __restrict__ Qh, const _Float16* __restrict__ Kh,
    const _Float16* __restrict__ Vt, const int* __restrict__ mask,
    float* __restrict__ out)
{
    __shared__ __align__(16) _Float16 QPs[64 * 512];      // 64 KB: Q, then P
    __shared__ __align__(16) _Float16 Ks[8][2][64 * 32];  // 64 KB: K, then V
    __shared__ float red[8][64];
    __shared__ float red2[8][64];
    const int tid = threadIdx.x, l = tid & 63, w = tid >> 6;   // w in 0..7
    const int lin = blockIdx.x;
    const int tb = (lin & 7) * 32 + (lin >> 3);   // XCD c -> batch b == c
    const int b = tb >> 5, a0 = (tb & 31) * 64;
    const _Float16* Qb = Qh + (size_t)(b * ALEN + a0) * HIDDEN;
    const _Float16* Kb = Kh + (size_t)b * TLEN * HIDDEN;
    const _Float16* Vb = Vt + (size_t)b * TLEN * HIDDEN;  // [h][t]
    const int srow = l >> 2, sj = l & 3;
    const int q = l >> 4, c16 = l & 15;

    // mask to regs up front (keeps loop vmcnt counts deterministic)
    int mv[4];
#pragma unroll
    for (int ni = 0; ni < 4; ni++)
        mv[ni] = mask[b * TLEN + w * 64 + ni * 16 + c16];

    // ---- stage Q (shared, once): wave w stages rows [w*8, w*8+8).
    // LDS chunk slot s of row r holds global chunk s ^ (r&7)  (chunk=16B).
#pragma unroll
    for (int i = 0; i < 8; i++) {
        int r = w * 8 + i;
        gload_lds16(Qb + (size_t)r * 512 + ((l ^ (r & 7)) << 3), &QPs[r * 512]);
    }
    // K prologue into private double buffer (drained by the barrier too)
    STAGE64(Kb, 0, Ks[w][0]);
    STAGE64(Kb, 32, Ks[w][1]);
    __syncthreads();   // publish Q; vmcnt drains to 0 here

    // ---------------- QK^T: barrier-free, double-buffered ----------------
    floatx4 acc[4][4] = {};
#pragma unroll
    for (int ks = 0; ks < 16; ks++) {
        const int k0 = ks * 32;
        if (ks == 15) { VMCNT(0); } else { VMCNT(4); }
        half8 af[4], bf[4];
        const _Float16* kb = &Ks[w][ks & 1][0];
#pragma unroll
        for (int t = 0; t < 4; t++) {
            int rA = t * 16 + c16;
            af[t] = *(const half8*)&QPs[rA * 512 + ((((k0 >> 3) + q) ^ (rA & 7)) << 3)];
            bf[t] = *(const half8*)&kb[rA * 32 + ((q ^ swz(rA)) << 3)];
        }
#pragma unroll
        for (int mi = 0; mi < 4; mi++)
#pragma unroll
            for (int ni = 0; ni < 4; ni++)
                acc[mi][ni] = __builtin_amdgcn_mfma_f32_16x16x32_f16(
                    af[mi], bf[ni], acc[mi][ni], 0, 0, 0);
        if (ks < 14) STAGE64(Kb, k0 + 64, Ks[w][ks & 1]);   // stage step ks+2
    }

    // V prologue NOW: latency hides under softmax (barrier drains it there)
    STAGE64(Vb, 0, Ks[w][0]);
    STAGE64(Vb, 32, Ks[w][1]);

    // ---------------- mask + softmax ----------------
    const float scale = 0.044194173824159216f;   // 512^-0.5
#pragma unroll
    for (int mi = 0; mi < 4; mi++)
#pragma unroll
        for (int ni = 0; ni < 4; ni++)
#pragma unroll
            for (int r = 0; r < 4; r++)
                acc[mi][ni][r] = mv[ni] ? acc[mi][ni][r] * scale : -1e30f;

    float mx[4][4];
#pragma unroll
    for (int mi = 0; mi < 4; mi++)
#pragma unroll
        for (int r = 0; r < 4; r++) {
            float m = -1e30f;
#pragma unroll
            for (int ni = 0; ni < 4; ni++) m = fmaxf(m, acc[mi][ni][r]);
#pragma unroll
            for (int off = 1; off <= 8; off <<= 1) m = fmaxf(m, __shfl_xor(m, off));
            mx[mi][r] = m;
        }
    if (c16 == 0)
#pragma unroll
        for (int mi = 0; mi < 4; mi++)
#pragma unroll
            for (int r = 0; r < 4; r++) red[w][mi * 16 + q * 4 + r] = mx[mi][r];
    __syncthreads();
#pragma unroll
    for (int mi = 0; mi < 4; mi++)
#pragma unroll
        for (int r = 0; r < 4; r++) {
            int row = mi * 16 + q * 4 + r;
            float m = red[0][row];
#pragma unroll
            for (int ww = 1; ww < 8; ww++) m = fmaxf(m, red[ww][row]);
            mx[mi][r] = m;
        }

    float sm[4][4];
#pragma unroll
    for (int mi = 0; mi < 4; mi++)
#pragma unroll
        for (int r = 0; r < 4; r++) {
            float s = 0.f;
#pragma unroll
            for (int ni = 0; ni < 4; ni++) {
                float e = __expf(acc[mi][ni][r] - mx[mi][r]);
                acc[mi][ni][r] = e;
                s += e;
            }
#pragma unroll
            for (int off = 1; off <= 8; off <<= 1) s += __shfl_xor(s, off);
            sm[mi][r] = s;
        }
    if (c16 == 0)
#pragma unroll
        for (int mi = 0; mi < 4; mi++)
#pragma unroll
            for (int r = 0; r < 4; r++) red2[w][mi * 16 + q * 4 + r] = sm[mi][r];
    __syncthreads();

    // ---------------- P -> LDS (overwrites Q; all Q reads done) ----------
    // Element (row,col) at chunk slot (col>>3) ^ (row&7), offset col&7.
    _Float16* Ps = QPs;
#pragma unroll
    for (int mi = 0; mi < 4; mi++)
#pragma unroll
        for (int r = 0; r < 4; r++) {
            int row = mi * 16 + q * 4 + r;
            float s = red2[0][row];
#pragma unroll
            for (int ww = 1; ww < 8; ww++) s += red2[ww][row];
            float inv = 1.f / s;
#pragma unroll
            for (int ni = 0; ni < 4; ni++) {
                int col = w * 64 + ni * 16 + c16;
                Ps[row * 512 + ((((col >> 3) ^ (row & 7)) << 3) + (col & 7))] =
                    (_Float16)(acc[mi][ni][r] * inv);
            }
        }
    __syncthreads();   // publish P (cross-wave read in PV)

    // ---------------- PV: barrier-free, double-buffered ----------------
    // out[a][h] = sum_t P[a][t] * Vt[h][t]; V in own Ks half-buffers.
    floatx4 oacc[4][4] = {};
#pragma unroll
    for (int ts = 0; ts < 16; ts++) {
        const int t0 = ts * 32;
        if (ts == 15) { VMCNT(0); } else { VMCNT(4); }
        half8 af[4], bf[4];
        const _Float16* vb = &Ks[w][ts & 1][0];
#pragma unroll
        for (int t = 0; t < 4; t++) {
            int rA = t * 16 + c16;
            af[t] = *(const half8*)&Ps[rA * 512 + ((((t0 >> 3) + q) ^ (rA & 7)) << 3)];
            bf[t] = *(const half8*)&vb[rA * 32 + ((q ^ swz(rA)) << 3)];
        }
#pragma unroll
        for (int mi = 0; mi < 4; mi++)
#pragma unroll
            for (int ni = 0; ni < 4; ni++)
                oacc[mi][ni] = __builtin_amdgcn_mfma_f32_16x16x32_f16(
                    af[mi], bf[ni], oacc[mi][ni], 0, 0, 0);
        if (ts < 14) STAGE64(Vb, t0 + 64, Ks[w][ts & 1]);   // stage step ts+2
    }

    // ---------------- epilogue: fp32 out, NON-TEMPORAL ----------------
    float* Ob = out + (size_t)(b * ALEN + a0) * HIDDEN;
#pragma unroll
    for (int ni = 0; ni < 4; ni++) {
        int col = w * 64 + ni * 16 + c16;
#pragma unroll
        for (int mi = 0; mi < 4; mi++) {
            int row = mi * 16 + q * 4;
#pragma unroll
            for (int r = 0; r < 4; r++)
                __builtin_nontemporal_store(oacc[mi][ni][r],
                                            &Ob[(size_t)(row + r) * HIDDEN + col]);
        }
    }
}

// ---------------------------------------------------------------------------
extern "C" void kernel_launch(void* const* d_in, const int* in_sizes, int n_in,
                              void* d_out, int out_size, void* d_ws, size_t ws_size,
                              hipStream_t stream)
{
    const float* audio = (const float*)d_in[0];   // [8,2048,512]
    const float* text  = (const float*)d_in[1];   // [8,512,768]
    const float* Wq    = (const float*)d_in[2];   // [512,512]
    const float* bq    = (const float*)d_in[3];
    const float* Wk    = (const float*)d_in[4];   // [768,512]
    const float* bk    = (const float*)d_in[5];
    const float* Wv    = (const float*)d_in[6];   // [768,512]
    const float* bv    = (const float*)d_in[7];
    const int*   maskp = (const int*)d_in[8];     // [8,512]
    float* out = (float*)d_out;

    // d_out doubles as f16 scratch until attn overwrites it:
    //   [8.39M .. 16.78M) halfs: Qh
    _Float16* Qh = (_Float16*)d_out + (size_t)8388608;

    // ws layout (halfs)
    _Float16* ws16   = (_Float16*)d_ws;
    _Float16* text_h = ws16;                        // 3,145,728  [B*512][768]
    _Float16* Wq_t   = text_h + 3145728;            //   262,144  [512][512]
    _Float16* Wk_t   = Wq_t + 262144;               //   393,216  [512][768]
    _Float16* Wv_t   = Wk_t + 393216;               //   393,216  [512][768]
    _Float16* Kh     = Wv_t + 393216;               // 2,097,152  [B,512,512]
    _Float16* Vt     = Kh + 2097152;                // 2,097,152  [B,512(h),512(t)]

    // 1) text cvt + weight transposes (audio cvt fused into qkv)
    prep<<<4096, 256, 0, stream>>>(text, Wq, Wk, Wv,
                                   text_h, Wq_t, Wk_t, Wv_t);
    // 2) Q + K + V^T GEMMs in one dispatch (Q reads audio fp32 via nt loads)
    qkv_gemm<<<768, 256, 0, stream>>>(audio, text_h, Wq_t, Wk_t, Wv_t,
                                      bq, bk, bv, Qh, Kh, Vt);
    // 3) fused scores+softmax+PV: 256 blocks x 512 thr, batch-per-XCD
    attn<<<256, 512, 0, stream>>>(Qh, Kh, Vt, maskp, out);
}